// Round 3
// baseline (370.764 us; speedup 1.0000x reference)
//
#include <hip/hip_runtime.h>

constexpr int N    = 50000;
constexpr int E    = 800000;
constexpr int CIN  = 128;
constexpr int COUT = 64;
constexpr float SELF_LOOP_W = 2.0f;

typedef float vfloat4 __attribute__((ext_vector_type(4)));

// ---------------------------------------------------------------------------
// 1) deg[n]=2.0, cnt[n]=0
__global__ void init_kernel(float* __restrict__ deg, int* __restrict__ cnt) {
    int i = blockIdx.x * blockDim.x + threadIdx.x;
    if (i < N) { deg[i] = SELF_LOOP_W; cnt[i] = 0; }
}

// 2) histogram: deg[col] += ew ; cnt[col] += 1
__global__ void hist_kernel(const int* __restrict__ col,
                            const float* __restrict__ ew,
                            float* __restrict__ deg, int* __restrict__ cnt) {
    int e = blockIdx.x * blockDim.x + threadIdx.x;
    if (e < E) {
        int c = col[e];
        atomicAdd(&deg[c], ew[e]);
        atomicAdd(&cnt[c], 1);
    }
}

// 3) deg -> dinv in place
__global__ void dinv_kernel(float* __restrict__ deg) {
    int i = blockIdx.x * blockDim.x + threadIdx.x;
    if (i < N) {
        float d = deg[i];
        deg[i] = (d > 0.f) ? rsqrtf(d) : 0.f;
    }
}

// 4) exclusive scan of cnt -> off[0..N], pos (mutable copy). Single block.
__global__ __launch_bounds__(1024) void scan_kernel(const int* __restrict__ cnt,
                                                    int* __restrict__ off,
                                                    int* __restrict__ pos) {
    __shared__ int lsum[1024];
    const int t  = threadIdx.x;
    const int CH = (N + 1023) / 1024;           // 49
    const int s0 = t * CH;
    const int s1 = min(s0 + CH, N);
    int sum = 0;
    for (int i = s0; i < s1; ++i) sum += cnt[i];
    lsum[t] = sum;
    __syncthreads();
    for (int d = 1; d < 1024; d <<= 1) {        // Hillis-Steele inclusive
        int v = (t >= d) ? lsum[t - d] : 0;
        __syncthreads();
        lsum[t] += v;
        __syncthreads();
    }
    int run = (t == 0) ? 0 : lsum[t - 1];       // exclusive prefix for chunk
    for (int i = s0; i < s1; ++i) {
        off[i] = run; pos[i] = run;
        run += cnt[i];
    }
    if (t == 0) off[N] = E;
}

// ---------------------------------------------------------------------------
// 5) xw = x @ W fused with out = 2*dinv^2*xw + b
// 64 nodes x 64 ch per block, 256 threads, 4x4 register tile per thread.
__global__ __launch_bounds__(256) void xw_fused_kernel(const float* __restrict__ x,
                                                       const float* __restrict__ W,
                                                       const float* __restrict__ dinv,
                                                       const float* __restrict__ b,
                                                       float* __restrict__ xw,
                                                       float* __restrict__ out) {
    __shared__ __align__(16) float xs[64][132];

    const int t    = threadIdx.x;
    const int base = blockIdx.x * 64;

    #pragma unroll
    for (int i = 0; i < 8; ++i) {
        int f4  = i * 256 + t;
        int row = f4 >> 5;
        int c4  = f4 & 31;
        int node = base + row;
        if (node >= N) node = N - 1;
        vfloat4 v = *(const vfloat4*)(x + (size_t)node * CIN + c4 * 4);
        *(vfloat4*)&xs[row][c4 * 4] = v;
    }
    __syncthreads();

    const int tc = t & 15;
    const int tn = t >> 4;

    float acc[4][4];
    #pragma unroll
    for (int i = 0; i < 4; ++i)
        #pragma unroll
        for (int j = 0; j < 4; ++j) acc[i][j] = 0.f;

    const float* Wp = W + tc * 4;
    #pragma unroll 8
    for (int k = 0; k < CIN; ++k) {
        vfloat4 bv = *(const vfloat4*)(Wp + (size_t)k * COUT);
        float a0 = xs[tn * 4 + 0][k];
        float a1 = xs[tn * 4 + 1][k];
        float a2 = xs[tn * 4 + 2][k];
        float a3 = xs[tn * 4 + 3][k];
        #pragma unroll
        for (int j = 0; j < 4; ++j) {
            acc[0][j] += a0 * bv[j];
            acc[1][j] += a1 * bv[j];
            acc[2][j] += a2 * bv[j];
            acc[3][j] += a3 * bv[j];
        }
    }

    vfloat4 bias = *(const vfloat4*)(b + tc * 4);
    #pragma unroll
    for (int i = 0; i < 4; ++i) {
        int node = base + tn * 4 + i;
        if (node >= N) continue;
        float di = dinv[node];
        float s  = SELF_LOOP_W * di * di;
        vfloat4 xv, ov;
        #pragma unroll
        for (int j = 0; j < 4; ++j) {
            xv[j] = acc[i][j];
            ov[j] = s * acc[i][j] + bias[j];
        }
        *(vfloat4*)(xw  + (size_t)node * COUT + tc * 4) = xv;
        *(vfloat4*)(out + (size_t)node * COUT + tc * 4) = ov;
    }
}

// ---------------------------------------------------------------------------
// 6) bucket-scatter edges by target: rs[p]=row, ns[p]=norm
__global__ void scatter_sort_kernel(const int* __restrict__ row,
                                    const int* __restrict__ col,
                                    const float* __restrict__ ew,
                                    const float* __restrict__ dinv,
                                    int* __restrict__ pos,
                                    int* __restrict__ rs,
                                    float* __restrict__ ns) {
    int e = blockIdx.x * blockDim.x + threadIdx.x;
    if (e < E) {
        int r = row[e];
        int c = col[e];
        float nrm = dinv[r] * ew[e] * dinv[c];
        int p = atomicAdd(&pos[c], 1);
        rs[p] = r;
        ns[p] = nrm;
    }
}

// 7) segment-reduce: one wave per node, lane = channel; no atomics.
__global__ __launch_bounds__(256) void gather_kernel(const int* __restrict__ off,
                                                     const int* __restrict__ rs,
                                                     const float* __restrict__ ns,
                                                     const float* __restrict__ xw,
                                                     float* __restrict__ out) {
    const int lane = threadIdx.x & 63;
    const int node = blockIdx.x * 4 + (threadIdx.x >> 6);
    if (node >= N) return;

    const int s   = off[node];
    const int end = off[node + 1];

    float acc = 0.f;
    for (int j0 = s; j0 < end; j0 += 64) {
        int j = j0 + lane;
        int   rr = 0;
        float nn = 0.f;
        if (j < end) { rr = rs[j]; nn = ns[j]; }
        int cnt = min(64, end - j0);
        int i = 0;
        for (; i + 4 <= cnt; i += 4) {
            int   r0 = __shfl(rr, i + 0), r1 = __shfl(rr, i + 1);
            int   r2 = __shfl(rr, i + 2), r3 = __shfl(rr, i + 3);
            float n0 = __shfl(nn, i + 0), n1 = __shfl(nn, i + 1);
            float n2 = __shfl(nn, i + 2), n3 = __shfl(nn, i + 3);
            float v0 = xw[(size_t)r0 * COUT + lane];
            float v1 = xw[(size_t)r1 * COUT + lane];
            float v2 = xw[(size_t)r2 * COUT + lane];
            float v3 = xw[(size_t)r3 * COUT + lane];
            acc += n0 * v0; acc += n1 * v1; acc += n2 * v2; acc += n3 * v3;
        }
        for (; i < cnt; ++i) {
            int   ri = __shfl(rr, i);
            float ni = __shfl(nn, i);
            acc += ni * xw[(size_t)ri * COUT + lane];
        }
    }
    out[(size_t)node * COUT + lane] += acc;   // self+bias already written
}

// ---------------------------------------------------------------------------
extern "C" void kernel_launch(void* const* d_in, const int* in_sizes, int n_in,
                              void* d_out, int out_size, void* d_ws, size_t ws_size,
                              hipStream_t stream) {
    const float* x  = (const float*)d_in[0];
    const int*   ei = (const int*)d_in[1];   // [2, E] int32
    const float* ew = (const float*)d_in[2];
    const float* W  = (const float*)d_in[3];
    const float* b  = (const float*)d_in[4];
    float* out = (float*)d_out;

    // ws layout
    float* xw  = (float*)d_ws;                       // N*COUT
    float* deg = xw + (size_t)N * COUT;              // N
    int*   cnt = (int*)(deg + N);                    // N
    int*   off = cnt + N;                            // N+1
    int*   pos = off + N + 1;                        // N
    int*   rs  = pos + N;                            // E
    float* ns  = (float*)(rs + E);                   // E

    const int* rowp = ei;
    const int* colp = ei + E;

    init_kernel        <<<(N + 255) / 256, 256, 0, stream>>>(deg, cnt);
    hist_kernel        <<<(E + 255) / 256, 256, 0, stream>>>(colp, ew, deg, cnt);
    dinv_kernel        <<<(N + 255) / 256, 256, 0, stream>>>(deg);
    scan_kernel        <<<1, 1024, 0, stream>>>(cnt, off, pos);
    xw_fused_kernel    <<<(N + 63) / 64, 256, 0, stream>>>(x, W, deg, b, xw, out);
    scatter_sort_kernel<<<(E + 255) / 256, 256, 0, stream>>>(rowp, colp, ew, deg, pos, rs, ns);
    gather_kernel      <<<(N + 3) / 4, 256, 0, stream>>>(off, rs, ns, xw, out);
}

// Round 4
// 267.278 us; speedup vs baseline: 1.3872x; 1.3872x over previous
//
#include <hip/hip_runtime.h>

constexpr int N    = 50000;
constexpr int E    = 800000;
constexpr int CIN  = 128;
constexpr int COUT = 64;
constexpr float SELF_LOOP_W = 2.0f;

constexpr int SCAN_B  = 512;                 // threads per scan block
constexpr int SCAN_NB = (N + SCAN_B - 1) / SCAN_B;   // 98 blocks

typedef float vfloat4 __attribute__((ext_vector_type(4)));

// ---------------------------------------------------------------------------
__global__ void init_kernel(float* __restrict__ deg, int* __restrict__ cnt) {
    int i = blockIdx.x * blockDim.x + threadIdx.x;
    if (i < N) { deg[i] = SELF_LOOP_W; cnt[i] = 0; }
}

__global__ void hist_kernel(const int* __restrict__ col,
                            const float* __restrict__ ew,
                            float* __restrict__ deg, int* __restrict__ cnt) {
    int e = blockIdx.x * blockDim.x + threadIdx.x;
    if (e < E) {
        int c = col[e];
        atomicAdd(&deg[c], ew[e]);
        atomicAdd(&cnt[c], 1);
    }
}

__global__ void dinv_kernel(float* __restrict__ deg) {
    int i = blockIdx.x * blockDim.x + threadIdx.x;
    if (i < N) {
        float d = deg[i];
        deg[i] = (d > 0.f) ? rsqrtf(d) : 0.f;
    }
}

// ---------------------------------------------------------------------------
// Two-level exclusive scan of cnt -> off (+ pos copy), off[N]=E.
__global__ __launch_bounds__(SCAN_B) void scan1_kernel(const int* __restrict__ cnt,
                                                       int* __restrict__ off,
                                                       int* __restrict__ bsum) {
    __shared__ int ls[SCAN_B];
    const int t = threadIdx.x;
    const int i = blockIdx.x * SCAN_B + t;
    int v = (i < N) ? cnt[i] : 0;
    ls[t] = v;
    __syncthreads();
    #pragma unroll
    for (int d = 1; d < SCAN_B; d <<= 1) {
        int u = (t >= d) ? ls[t - d] : 0;
        __syncthreads();
        ls[t] += u;
        __syncthreads();
    }
    if (i < N) off[i] = ls[t] - v;            // exclusive within block
    if (t == SCAN_B - 1) bsum[blockIdx.x] = ls[t];
}

__global__ __launch_bounds__(128) void scan2_kernel(int* __restrict__ bsum) {
    __shared__ int ls[128];
    const int t = threadIdx.x;
    int v = (t < SCAN_NB) ? bsum[t] : 0;
    ls[t] = v;
    __syncthreads();
    #pragma unroll
    for (int d = 1; d < 128; d <<= 1) {
        int u = (t >= d) ? ls[t - d] : 0;
        __syncthreads();
        ls[t] += u;
        __syncthreads();
    }
    if (t < SCAN_NB) bsum[t] = ls[t] - v;     // exclusive block offsets
}

__global__ __launch_bounds__(SCAN_B) void scan3_kernel(int* __restrict__ off,
                                                       int* __restrict__ pos,
                                                       const int* __restrict__ bsum) {
    const int t = threadIdx.x;
    const int i = blockIdx.x * SCAN_B + t;
    if (i < N) {
        int o = off[i] + bsum[blockIdx.x];
        off[i] = o;
        pos[i] = o;
    }
    if (i == 0) off[N] = E;
}

// ---------------------------------------------------------------------------
// xw = x @ W fused with out = 2*dinv^2*xw + b
__global__ __launch_bounds__(256) void xw_fused_kernel(const float* __restrict__ x,
                                                       const float* __restrict__ W,
                                                       const float* __restrict__ dinv,
                                                       const float* __restrict__ b,
                                                       float* __restrict__ xw,
                                                       float* __restrict__ out) {
    __shared__ __align__(16) float xs[64][132];

    const int t    = threadIdx.x;
    const int base = blockIdx.x * 64;

    #pragma unroll
    for (int i = 0; i < 8; ++i) {
        int f4  = i * 256 + t;
        int row = f4 >> 5;
        int c4  = f4 & 31;
        int node = base + row;
        if (node >= N) node = N - 1;
        vfloat4 v = *(const vfloat4*)(x + (size_t)node * CIN + c4 * 4);
        *(vfloat4*)&xs[row][c4 * 4] = v;
    }
    __syncthreads();

    const int tc = t & 15;
    const int tn = t >> 4;

    float acc[4][4];
    #pragma unroll
    for (int i = 0; i < 4; ++i)
        #pragma unroll
        for (int j = 0; j < 4; ++j) acc[i][j] = 0.f;

    const float* Wp = W + tc * 4;
    #pragma unroll 8
    for (int k = 0; k < CIN; ++k) {
        vfloat4 bv = *(const vfloat4*)(Wp + (size_t)k * COUT);
        float a0 = xs[tn * 4 + 0][k];
        float a1 = xs[tn * 4 + 1][k];
        float a2 = xs[tn * 4 + 2][k];
        float a3 = xs[tn * 4 + 3][k];
        #pragma unroll
        for (int j = 0; j < 4; ++j) {
            acc[0][j] += a0 * bv[j];
            acc[1][j] += a1 * bv[j];
            acc[2][j] += a2 * bv[j];
            acc[3][j] += a3 * bv[j];
        }
    }

    vfloat4 bias = *(const vfloat4*)(b + tc * 4);
    #pragma unroll
    for (int i = 0; i < 4; ++i) {
        int node = base + tn * 4 + i;
        if (node >= N) continue;
        float di = dinv[node];
        float s  = SELF_LOOP_W * di * di;
        vfloat4 xv, ov;
        #pragma unroll
        for (int j = 0; j < 4; ++j) {
            xv[j] = acc[i][j];
            ov[j] = s * acc[i][j] + bias[j];
        }
        *(vfloat4*)(xw  + (size_t)node * COUT + tc * 4) = xv;
        *(vfloat4*)(out + (size_t)node * COUT + tc * 4) = ov;
    }
}

// ---------------------------------------------------------------------------
__global__ void scatter_sort_kernel(const int* __restrict__ row,
                                    const int* __restrict__ col,
                                    const float* __restrict__ ew,
                                    const float* __restrict__ dinv,
                                    int* __restrict__ pos,
                                    int* __restrict__ rs,
                                    float* __restrict__ ns) {
    int e = blockIdx.x * blockDim.x + threadIdx.x;
    if (e < E) {
        int r = row[e];
        int c = col[e];
        float nrm = dinv[r] * ew[e] * dinv[c];
        int p = atomicAdd(&pos[c], 1);
        rs[p] = r;
        ns[p] = nrm;
    }
}

// segment-reduce: one wave per node, lane = channel; no atomics.
__global__ __launch_bounds__(256) void gather_kernel(const int* __restrict__ off,
                                                     const int* __restrict__ rs,
                                                     const float* __restrict__ ns,
                                                     const float* __restrict__ xw,
                                                     float* __restrict__ out) {
    const int lane = threadIdx.x & 63;
    const int node = blockIdx.x * 4 + (threadIdx.x >> 6);
    if (node >= N) return;

    const int s   = off[node];
    const int end = off[node + 1];

    float acc = 0.f;
    for (int j0 = s; j0 < end; j0 += 64) {
        int j = j0 + lane;
        int   rr = 0;
        float nn = 0.f;
        if (j < end) { rr = rs[j]; nn = ns[j]; }
        int cnt = min(64, end - j0);
        int i = 0;
        for (; i + 4 <= cnt; i += 4) {
            int   r0 = __shfl(rr, i + 0), r1 = __shfl(rr, i + 1);
            int   r2 = __shfl(rr, i + 2), r3 = __shfl(rr, i + 3);
            float n0 = __shfl(nn, i + 0), n1 = __shfl(nn, i + 1);
            float n2 = __shfl(nn, i + 2), n3 = __shfl(nn, i + 3);
            float v0 = xw[(size_t)r0 * COUT + lane];
            float v1 = xw[(size_t)r1 * COUT + lane];
            float v2 = xw[(size_t)r2 * COUT + lane];
            float v3 = xw[(size_t)r3 * COUT + lane];
            acc += n0 * v0; acc += n1 * v1; acc += n2 * v2; acc += n3 * v3;
        }
        for (; i < cnt; ++i) {
            int   ri = __shfl(rr, i);
            float ni = __shfl(nn, i);
            acc += ni * xw[(size_t)ri * COUT + lane];
        }
    }
    out[(size_t)node * COUT + lane] += acc;
}

// ---------------------------------------------------------------------------
extern "C" void kernel_launch(void* const* d_in, const int* in_sizes, int n_in,
                              void* d_out, int out_size, void* d_ws, size_t ws_size,
                              hipStream_t stream) {
    const float* x  = (const float*)d_in[0];
    const int*   ei = (const int*)d_in[1];   // [2, E] int32
    const float* ew = (const float*)d_in[2];
    const float* W  = (const float*)d_in[3];
    const float* b  = (const float*)d_in[4];
    float* out = (float*)d_out;

    // ws layout
    float* xw   = (float*)d_ws;                      // N*COUT
    float* deg  = xw + (size_t)N * COUT;             // N
    int*   cnt  = (int*)(deg + N);                   // N
    int*   off  = cnt + N;                           // N+1
    int*   pos  = off + N + 1;                       // N
    int*   bsum = pos + N;                           // SCAN_NB
    int*   rs   = bsum + SCAN_NB;                    // E
    float* ns   = (float*)(rs + E);                  // E

    const int* rowp = ei;
    const int* colp = ei + E;

    init_kernel        <<<(N + 255) / 256, 256, 0, stream>>>(deg, cnt);
    hist_kernel        <<<(E + 255) / 256, 256, 0, stream>>>(colp, ew, deg, cnt);
    dinv_kernel        <<<(N + 255) / 256, 256, 0, stream>>>(deg);
    scan1_kernel       <<<SCAN_NB, SCAN_B, 0, stream>>>(cnt, off, bsum);
    scan2_kernel       <<<1, 128, 0, stream>>>(bsum);
    scan3_kernel       <<<SCAN_NB, SCAN_B, 0, stream>>>(off, pos, bsum);
    xw_fused_kernel    <<<(N + 63) / 64, 256, 0, stream>>>(x, W, deg, b, xw, out);
    scatter_sort_kernel<<<(E + 255) / 256, 256, 0, stream>>>(rowp, colp, ew, deg, pos, rs, ns);
    gather_kernel      <<<(N + 3) / 4, 256, 0, stream>>>(off, rs, ns, xw, out);
}

// Round 5
// 226.503 us; speedup vs baseline: 1.6369x; 1.1800x over previous
//
#include <hip/hip_runtime.h>

constexpr int N    = 50000;
constexpr int E    = 800000;
constexpr int CIN  = 128;
constexpr int COUT = 64;
constexpr float SELF_LOOP_W = 2.0f;
constexpr int REP  = 8;                       // histogram replicas

constexpr int SCAN_B  = 512;
constexpr int SCAN_NB = (N + SCAN_B - 1) / SCAN_B;   // 98

typedef float vfloat4 __attribute__((ext_vector_type(4)));

// ---------------------------------------------------------------------------
__global__ void zero_kernel(int* __restrict__ cnt) {
    int i = blockIdx.x * blockDim.x + threadIdx.x;
    if (i < REP * N) cnt[i] = 0;
}

// cnt[e&7][col[e]]++  (one atomic per edge, 8-way spread)
__global__ void hist_kernel(const int* __restrict__ col,
                            int* __restrict__ cnt) {
    int e = blockIdx.x * blockDim.x + threadIdx.x;
    if (e < E) {
        int c = col[e];
        atomicAdd(&cnt[(e & (REP - 1)) * N + c], 1);
    }
}

// ---------------------------------------------------------------------------
// two-level exclusive scan of tot[c]=sum_r cnt[r][c]; scan3 also derives pos[r][c]
__global__ __launch_bounds__(SCAN_B) void scan1_kernel(const int* __restrict__ cnt,
                                                       int* __restrict__ off,
                                                       int* __restrict__ bsum) {
    __shared__ int ls[SCAN_B];
    const int t = threadIdx.x;
    const int i = blockIdx.x * SCAN_B + t;
    int v = 0;
    if (i < N) {
        #pragma unroll
        for (int r = 0; r < REP; ++r) v += cnt[r * N + i];
    }
    ls[t] = v;
    __syncthreads();
    #pragma unroll
    for (int d = 1; d < SCAN_B; d <<= 1) {
        int u = (t >= d) ? ls[t - d] : 0;
        __syncthreads();
        ls[t] += u;
        __syncthreads();
    }
    if (i < N) off[i] = ls[t] - v;
    if (t == SCAN_B - 1) bsum[blockIdx.x] = ls[t];
}

__global__ __launch_bounds__(128) void scan2_kernel(int* __restrict__ bsum) {
    __shared__ int ls[128];
    const int t = threadIdx.x;
    int v = (t < SCAN_NB) ? bsum[t] : 0;
    ls[t] = v;
    __syncthreads();
    #pragma unroll
    for (int d = 1; d < 128; d <<= 1) {
        int u = (t >= d) ? ls[t - d] : 0;
        __syncthreads();
        ls[t] += u;
        __syncthreads();
    }
    if (t < SCAN_NB) bsum[t] = ls[t] - v;
}

__global__ __launch_bounds__(SCAN_B) void scan3_kernel(int* __restrict__ off,
                                                       int* __restrict__ pos,
                                                       const int* __restrict__ cnt,
                                                       const int* __restrict__ bsum) {
    const int i = blockIdx.x * SCAN_B + threadIdx.x;
    if (i < N) {
        int o = off[i] + bsum[blockIdx.x];
        off[i] = o;
        int s = o;
        #pragma unroll
        for (int r = 0; r < REP; ++r) { pos[r * N + i] = s; s += cnt[r * N + i]; }
    }
    if (i == 0) off[N] = E;
}

// ---------------------------------------------------------------------------
// bucket-scatter (no dinv dependency): rs[p]=row, ns[p]=ew
__global__ void scatter_kernel(const int* __restrict__ row,
                               const int* __restrict__ col,
                               const float* __restrict__ ew,
                               int* __restrict__ pos,
                               int* __restrict__ rs,
                               float* __restrict__ ns) {
    int e = blockIdx.x * blockDim.x + threadIdx.x;
    if (e < E) {
        int c = col[e];
        int p = atomicAdd(&pos[(e & (REP - 1)) * N + c], 1);
        rs[p] = row[e];
        ns[p] = ew[e];
    }
}

// deg from sorted ew: dinv[c] = rsqrt(2 + sum seg)
__global__ void deg_kernel(const int* __restrict__ off,
                           const float* __restrict__ ns,
                           float* __restrict__ dinv) {
    int i = blockIdx.x * blockDim.x + threadIdx.x;
    if (i < N) {
        float s = SELF_LOOP_W;
        int e0 = off[i], e1 = off[i + 1];
        for (int j = e0; j < e1; ++j) s += ns[j];
        dinv[i] = rsqrtf(s);
    }
}

// ---------------------------------------------------------------------------
// pure GEMM: xw = x @ W  (64x64 tile, 4x4 per thread)
__global__ __launch_bounds__(256) void xw_kernel(const float* __restrict__ x,
                                                 const float* __restrict__ W,
                                                 float* __restrict__ xw) {
    __shared__ __align__(16) float xs[64][132];

    const int t    = threadIdx.x;
    const int base = blockIdx.x * 64;

    #pragma unroll
    for (int i = 0; i < 8; ++i) {
        int f4  = i * 256 + t;
        int row = f4 >> 5;
        int c4  = f4 & 31;
        int node = base + row;
        if (node >= N) node = N - 1;
        vfloat4 v = *(const vfloat4*)(x + (size_t)node * CIN + c4 * 4);
        *(vfloat4*)&xs[row][c4 * 4] = v;
    }
    __syncthreads();

    const int tc = t & 15;
    const int tn = t >> 4;

    float acc[4][4];
    #pragma unroll
    for (int i = 0; i < 4; ++i)
        #pragma unroll
        for (int j = 0; j < 4; ++j) acc[i][j] = 0.f;

    const float* Wp = W + tc * 4;
    #pragma unroll 8
    for (int k = 0; k < CIN; ++k) {
        vfloat4 bv = *(const vfloat4*)(Wp + (size_t)k * COUT);
        float a0 = xs[tn * 4 + 0][k];
        float a1 = xs[tn * 4 + 1][k];
        float a2 = xs[tn * 4 + 2][k];
        float a3 = xs[tn * 4 + 3][k];
        #pragma unroll
        for (int j = 0; j < 4; ++j) {
            acc[0][j] += a0 * bv[j];
            acc[1][j] += a1 * bv[j];
            acc[2][j] += a2 * bv[j];
            acc[3][j] += a3 * bv[j];
        }
    }

    #pragma unroll
    for (int i = 0; i < 4; ++i) {
        int node = base + tn * 4 + i;
        if (node >= N) continue;
        vfloat4 xv;
        #pragma unroll
        for (int j = 0; j < 4; ++j) xv[j] = acc[i][j];
        *(vfloat4*)(xw + (size_t)node * COUT + tc * 4) = xv;
    }
}

// ---------------------------------------------------------------------------
// main gather: out = dinv[c]*sum_j (dinv[r_j]*ew_j)*xw[r_j] + 2*dinv[c]^2*xw[c] + b
__global__ __launch_bounds__(256) void gather_kernel(const int* __restrict__ off,
                                                     const int* __restrict__ rs,
                                                     const float* __restrict__ ns,
                                                     const float* __restrict__ dinv,
                                                     const float* __restrict__ xw,
                                                     const float* __restrict__ b,
                                                     float* __restrict__ out) {
    const int lane = threadIdx.x & 63;
    const int node = blockIdx.x * 4 + (threadIdx.x >> 6);
    if (node >= N) return;

    const int s   = off[node];
    const int end = off[node + 1];

    float acc = 0.f;
    for (int j0 = s; j0 < end; j0 += 64) {
        int j = j0 + lane;
        int   rr = 0;
        float nn = 0.f;
        if (j < end) { rr = rs[j]; nn = ns[j] * dinv[rr]; }
        int cnt = min(64, end - j0);
        int i = 0;
        for (; i + 4 <= cnt; i += 4) {
            int   r0 = __shfl(rr, i + 0), r1 = __shfl(rr, i + 1);
            int   r2 = __shfl(rr, i + 2), r3 = __shfl(rr, i + 3);
            float n0 = __shfl(nn, i + 0), n1 = __shfl(nn, i + 1);
            float n2 = __shfl(nn, i + 2), n3 = __shfl(nn, i + 3);
            float v0 = xw[(size_t)r0 * COUT + lane];
            float v1 = xw[(size_t)r1 * COUT + lane];
            float v2 = xw[(size_t)r2 * COUT + lane];
            float v3 = xw[(size_t)r3 * COUT + lane];
            acc += n0 * v0; acc += n1 * v1; acc += n2 * v2; acc += n3 * v3;
        }
        for (; i < cnt; ++i) {
            int   ri = __shfl(rr, i);
            float ni = __shfl(nn, i);
            acc += ni * xw[(size_t)ri * COUT + lane];
        }
    }

    float dc = dinv[node];
    float self = SELF_LOOP_W * dc * dc * xw[(size_t)node * COUT + lane];
    out[(size_t)node * COUT + lane] = dc * acc + self + b[lane];
}

// ---------------------------------------------------------------------------
extern "C" void kernel_launch(void* const* d_in, const int* in_sizes, int n_in,
                              void* d_out, int out_size, void* d_ws, size_t ws_size,
                              hipStream_t stream) {
    const float* x  = (const float*)d_in[0];
    const int*   ei = (const int*)d_in[1];   // [2, E] int32
    const float* ew = (const float*)d_in[2];
    const float* W  = (const float*)d_in[3];
    const float* b  = (const float*)d_in[4];
    float* out = (float*)d_out;

    // ws layout
    float* xw   = (float*)d_ws;                      // N*COUT
    float* dinv = xw + (size_t)N * COUT;             // N
    int*   cnt  = (int*)(dinv + N);                  // REP*N
    int*   off  = cnt + REP * N;                     // N+1
    int*   pos  = off + N + 1;                       // REP*N
    int*   bsum = pos + REP * N;                     // SCAN_NB
    int*   rs   = bsum + SCAN_NB;                    // E
    float* ns   = (float*)(rs + E);                  // E

    const int* rowp = ei;
    const int* colp = ei + E;

    zero_kernel   <<<(REP * N + 255) / 256, 256, 0, stream>>>(cnt);
    hist_kernel   <<<(E + 255) / 256, 256, 0, stream>>>(colp, cnt);
    scan1_kernel  <<<SCAN_NB, SCAN_B, 0, stream>>>(cnt, off, bsum);
    scan2_kernel  <<<1, 128, 0, stream>>>(bsum);
    scan3_kernel  <<<SCAN_NB, SCAN_B, 0, stream>>>(off, pos, cnt, bsum);
    scatter_kernel<<<(E + 255) / 256, 256, 0, stream>>>(rowp, colp, ew, pos, rs, ns);
    xw_kernel     <<<(N + 63) / 64, 256, 0, stream>>>(x, W, xw);
    deg_kernel    <<<(N + 255) / 256, 256, 0, stream>>>(off, ns, dinv);
    gather_kernel <<<(N + 3) / 4, 256, 0, stream>>>(off, rs, ns, dinv, xw, b, out);
}